// Round 1
// baseline (47709.073 us; speedup 1.0000x reference)
//
#include <hip/hip_runtime.h>
#include <math.h>

#define T_ 128
#define B_ 32
#define V_ 33278
#define E_ 400

__device__ __forceinline__ float sigmoidf_(float x) { return 1.0f / (1.0f + expf(-x)); }

// ---------------- embedding gather ----------------
__global__ void embed_kernel(const int* __restrict__ idx, const float* __restrict__ W,
                             float* __restrict__ x) {
  int i = blockIdx.x * blockDim.x + threadIdx.x;  // over T*B*E
  if (i >= T_ * B_ * E_) return;
  int e = i % E_;
  int tb = i / E_;
  x[i] = W[idx[tb] * E_ + e];
}

// ---------------- fp32 tiled GEMM: C[M,N] = A[M,K] * B[N,K]^T + bias0 + bias1 ----------------
#define BM 64
#define BN 64
#define BK 16
__global__ __launch_bounds__(256) void gemm_tn(const float* __restrict__ A,
                                               const float* __restrict__ B,
                                               const float* __restrict__ bias0,
                                               const float* __restrict__ bias1,
                                               float* __restrict__ C, int M, int N, int K) {
  __shared__ float As[BK][BM];
  __shared__ float Bs[BK][BN];
  int tid = threadIdx.x;
  int tx = tid & 15, ty = tid >> 4;
  int m0 = blockIdx.y * BM, n0 = blockIdx.x * BN;
  float acc[4][4] = {};
  int row = tid >> 2, kq = (tid & 3) * 4;
  for (int kt = 0; kt < K; kt += BK) {
#pragma unroll
    for (int j = 0; j < 4; ++j) {
      int k = kt + kq + j;
      int m = m0 + row;
      As[kq + j][row] = (m < M && k < K) ? A[m * K + k] : 0.0f;
      int n = n0 + row;
      Bs[kq + j][row] = (n < N && k < K) ? B[n * K + k] : 0.0f;
    }
    __syncthreads();
#pragma unroll
    for (int kk = 0; kk < BK; ++kk) {
      float4 av = *(const float4*)&As[kk][ty * 4];
      float4 bv = *(const float4*)&Bs[kk][tx * 4];
      float a[4] = {av.x, av.y, av.z, av.w};
      float b[4] = {bv.x, bv.y, bv.z, bv.w};
#pragma unroll
      for (int i = 0; i < 4; ++i)
#pragma unroll
        for (int j = 0; j < 4; ++j) acc[i][j] += a[i] * b[j];
    }
    __syncthreads();
  }
#pragma unroll
  for (int i = 0; i < 4; ++i) {
    int m = m0 + ty * 4 + i;
    if (m >= M) continue;
#pragma unroll
    for (int j = 0; j < 4; ++j) {
      int n = n0 + tx * 4 + j;
      if (n >= N) continue;
      float v = acc[i][j];
      if (bias0) v += bias0[n];
      if (bias1) v += bias1[n];
      C[m * N + n] = v;
    }
  }
}

// ---------------- one LSTM timestep ----------------
// h_in / h_out / c stored transposed: [dh][B]  (coalesced over b)
// xg_t: [B, 4*dh] slice at timestep t (already contains x@Wih^T + bih + bhh)
// x_out_t: [B, dh] (layer output at timestep t)
__global__ __launch_bounds__(256) void lstm_step(const float* __restrict__ xg_t,
                                                 const float* __restrict__ Whh,
                                                 const float* __restrict__ h_in,
                                                 float* __restrict__ h_out,
                                                 float* __restrict__ c_t,
                                                 float* __restrict__ x_out_t, int dh) {
  int tid = threadIdx.x;
  int b = tid & 31;
  int gate = (tid >> 5) & 3;
  int ul = tid >> 7;  // 0 or 1
  int u = blockIdx.x * 2 + ul;
  int rowi = gate * dh + u;
  const float* wr = Whh + rowi * dh;
  float acc = xg_t[b * (4 * dh) + rowi];
  for (int k = 0; k < dh; k += 2) {
    float2 w = *(const float2*)&wr[k];
    acc += h_in[k * B_ + b] * w.x;
    acc += h_in[(k + 1) * B_ + b] * w.y;
  }
  __shared__ float red[2][4][32];
  red[ul][gate][b] = acc;
  __syncthreads();
  if (gate == 0) {
    float pi = red[ul][0][b], pf = red[ul][1][b], pg = red[ul][2][b], po = red[ul][3][b];
    float ig = sigmoidf_(pi), fg = sigmoidf_(pf), gg = tanhf(pg), og = sigmoidf_(po);
    float c = fg * c_t[u * B_ + b] + ig * gg;
    float h = og * tanhf(c);
    c_t[u * B_ + b] = c;
    h_out[u * B_ + b] = h;
    x_out_t[b * dh + u] = h;
  }
}

// ---------------- h0/c0 transpose-in ----------------
__global__ void init_hc(const float* __restrict__ h0, const float* __restrict__ c0,
                        float* __restrict__ h_t, float* __restrict__ c_t, int dh) {
  int i = blockIdx.x * blockDim.x + threadIdx.x;  // i = b*dh + u
  if (i >= dh * B_) return;
  int b = i / dh, u = i % dh;
  h_t[u * B_ + b] = h0[i];
  c_t[u * B_ + b] = c0[i];
}

// ---------------- hT/cT transpose-out ----------------
__global__ void writeout_hc(const float* __restrict__ h_t, const float* __restrict__ c_t,
                            float* __restrict__ out_h, float* __restrict__ out_c, int dh) {
  int i = blockIdx.x * blockDim.x + threadIdx.x;  // i = b*dh + u
  if (i >= dh * B_) return;
  int b = i / dh, u = i % dh;
  out_h[i] = h_t[u * B_ + b];
  out_c[i] = c_t[u * B_ + b];
}

extern "C" void kernel_launch(void* const* d_in, const int* in_sizes, int n_in, void* d_out,
                              int out_size, void* d_ws, size_t ws_size, hipStream_t stream) {
  const int* input = (const int*)d_in[0];
  const float* emb_W = (const float*)d_in[1];
  const float* final_b = (const float*)d_in[2];

  struct L {
    const float *Wih, *Whh, *bih, *bhh, *h0, *c0;
    int din, dh;
  };
  L ls[3];
  ls[0] = {(const float*)d_in[3],  (const float*)d_in[4],  (const float*)d_in[5],
           (const float*)d_in[6],  (const float*)d_in[7],  (const float*)d_in[8],  400, 1150};
  ls[1] = {(const float*)d_in[9],  (const float*)d_in[10], (const float*)d_in[11],
           (const float*)d_in[12], (const float*)d_in[13], (const float*)d_in[14], 1150, 1150};
  ls[2] = {(const float*)d_in[15], (const float*)d_in[16], (const float*)d_in[17],
           (const float*)d_in[18], (const float*)d_in[19], (const float*)d_in[20], 1150, 400};

  float* ws = (float*)d_ws;
  float* xg = ws;                              // 4096*4600
  float* xA = xg + 4096 * 4600;                // 4096*1150
  float* xB = xA + 4096 * 1150;                // 4096*1150
  float* hbuf0 = xB + 4096 * 1150;             // 1150*32
  float* hbuf1 = hbuf0 + 1150 * 32;            // 1150*32
  float* cbuf = hbuf1 + 1150 * 32;             // 1150*32
  float* out = (float*)d_out;

  // embedding -> xA [T*B, 400]
  embed_kernel<<<(T_ * B_ * E_ + 255) / 256, 256, 0, stream>>>(input, emb_W, xA);

  float* xcur = xA;
  float* xnext = xB;
  long outOff = (long)T_ * B_ * V_;

  for (int l = 0; l < 3; ++l) {
    int din = ls[l].din, dh = ls[l].dh, N4 = 4 * dh;
    dim3 g((N4 + BN - 1) / BN, 4096 / BM);
    gemm_tn<<<g, 256, 0, stream>>>(xcur, ls[l].Wih, ls[l].bih, ls[l].bhh, xg, 4096, N4, din);
    init_hc<<<(dh * B_ + 255) / 256, 256, 0, stream>>>(ls[l].h0, ls[l].c0, hbuf0, cbuf, dh);
    for (int t = 0; t < T_; ++t) {
      const float* hin = (t & 1) ? hbuf1 : hbuf0;
      float* hout = (t & 1) ? hbuf0 : hbuf1;
      lstm_step<<<dh / 2, 256, 0, stream>>>(xg + (long)t * B_ * N4, ls[l].Whh, hin, hout, cbuf,
                                            xnext + (long)t * B_ * dh, dh);
    }
    // after 128 steps the final h lives in hbuf0 (even count of swaps)
    writeout_hc<<<(dh * B_ + 255) / 256, 256, 0, stream>>>(hbuf0, cbuf, out + outOff,
                                                           out + outOff + B_ * dh, dh);
    outOff += 2L * B_ * dh;
    float* tmp = xcur;
    xcur = xnext;
    xnext = tmp;
  }

  // tied decoder: logits[4096, V] = x3 @ emb_W^T + final_b
  dim3 gd((V_ + BN - 1) / BN, 4096 / BM);
  gemm_tn<<<gd, 256, 0, stream>>>(xcur, emb_W, final_b, nullptr, out, 4096, V_, 400);
}

// Round 2
// 42559.531 us; speedup vs baseline: 1.1210x; 1.1210x over previous
//
#include <hip/hip_runtime.h>
#include <math.h>

#define T_ 128
#define B_ 32
#define V_ 33278
#define E_ 400

typedef __bf16 bf16x8 __attribute__((ext_vector_type(8)));
typedef float f32x4 __attribute__((ext_vector_type(4)));

__device__ __forceinline__ float sigmoidf_(float x) { return 1.0f / (1.0f + expf(-x)); }

__device__ __forceinline__ unsigned short f2bf(float f) {
  unsigned u = __float_as_uint(f);
  unsigned lsb = (u >> 16) & 1;
  return (unsigned short)((u + 0x7FFFu + lsb) >> 16);
}

__device__ __forceinline__ void gload16(const unsigned short* g, unsigned short* l) {
  __builtin_amdgcn_global_load_lds((const __attribute__((address_space(1))) void*)g,
                                   (__attribute__((address_space(3))) void*)l, 16, 0, 0);
}

// ---------------- embedding gather -> bf16 padded [T*B][416] ----------------
__global__ void embed_kernel(const int* __restrict__ idx, const float* __restrict__ W,
                             unsigned short* __restrict__ x) {
  int i = blockIdx.x * blockDim.x + threadIdx.x;  // over T*B*416
  if (i >= T_ * B_ * 416) return;
  int k = i % 416;
  int tb = i / 416;
  x[i] = (k < E_) ? f2bf(W[(size_t)idx[tb] * E_ + k]) : 0;
}

// ---------------- fp32 -> bf16 weight conversion with padding ----------------
__global__ void convW(const float* __restrict__ in, unsigned short* __restrict__ out, int N, int K,
                      int Kp, long total) {
  long i = (long)blockIdx.x * blockDim.x + threadIdx.x;
  if (i >= total) return;
  int k = (int)(i % Kp);
  long n = i / Kp;
  out[i] = (n < N && k < K) ? f2bf(in[n * (long)K + k]) : 0;
}

// ---------------- zero the K-padding columns of an activation buffer ----------------
__global__ void zpad(unsigned short* __restrict__ x, int ld, int k0) {
  int npad = ld - k0;
  int i = blockIdx.x * blockDim.x + threadIdx.x;
  if (i >= T_ * B_ * npad) return;
  int r = i / npad, k = k0 + i % npad;
  x[(size_t)r * ld + k] = 0;
}

// ---------------- bf16 MFMA GEMM: C[M,N] = A[M,Kp] * B[N,Kp]^T + bias ----------------
// A: [M][Kp] bf16 row-major, M % 128 == 0, Kp % 32 == 0
// B: [Npad][Kp] bf16 row-major (Npad % 128 == 0, zero-padded)
// C: [M][ldc] fp32, write guarded to n < realN
__global__ __launch_bounds__(256) void gemm_bf16(const unsigned short* __restrict__ A,
                                                 const unsigned short* __restrict__ B,
                                                 const float* __restrict__ bias0,
                                                 const float* __restrict__ bias1,
                                                 float* __restrict__ C, int M, int Kp, int ldc,
                                                 int realN) {
  __shared__ __align__(16) unsigned short lsA[4 * 128 * 8];  // [kc][row][8] = 8KB
  __shared__ __align__(16) unsigned short lsB[4 * 128 * 8];
  const int tid = threadIdx.x;
  const int lane = tid & 63;
  const int w = tid >> 6;           // wave 0..3
  const int wm = (w >> 1) * 64;     // wave's M offset in tile
  const int wn = (w & 1) * 64;      // wave's N offset in tile
  const int lr = lane & 15;
  const int kq = lane >> 4;  // 0..3
  const int m0 = blockIdx.y * 128;
  const int n0 = blockIdx.x * 128;

  f32x4 acc[4][4] = {};

  const int kiters = Kp >> 5;
  for (int kt = 0; kt < kiters; ++kt) {
    const int k0 = kt << 5;
    // stage A and B tiles: 8 segments each of 1024B; wave w does segs {w, w+4}
#pragma unroll
    for (int q = 0; q < 2; ++q) {
      int s = w + q * 4;
      int kc = s >> 1, rb = (s & 1) * 64;
      gload16(A + (size_t)(m0 + rb + lane) * Kp + k0 + kc * 8, lsA + s * 512);
      gload16(B + (size_t)(n0 + rb + lane) * Kp + k0 + kc * 8, lsB + s * 512);
    }
    __syncthreads();

    bf16x8 af[4], bf[4];
#pragma unroll
    for (int mf = 0; mf < 4; ++mf)
      af[mf] = *(const bf16x8*)&lsA[(kq * 128 + wm + mf * 16 + lr) * 8];
#pragma unroll
    for (int nf = 0; nf < 4; ++nf)
      bf[nf] = *(const bf16x8*)&lsB[(kq * 128 + wn + nf * 16 + lr) * 8];
#pragma unroll
    for (int mf = 0; mf < 4; ++mf)
#pragma unroll
      for (int nf = 0; nf < 4; ++nf)
        acc[mf][nf] = __builtin_amdgcn_mfma_f32_16x16x32_bf16(af[mf], bf[nf], acc[mf][nf], 0, 0, 0);
    __syncthreads();
  }

#pragma unroll
  for (int nf = 0; nf < 4; ++nf) {
    int n = n0 + wn + nf * 16 + lr;
    if (n >= realN) continue;
    float bsum = 0.0f;
    if (bias0) bsum += bias0[n];
    if (bias1) bsum += bias1[n];
#pragma unroll
    for (int mf = 0; mf < 4; ++mf) {
      int mbase = m0 + wm + mf * 16 + kq * 4;
#pragma unroll
      for (int r = 0; r < 4; ++r) C[(size_t)(mbase + r) * ldc + n] = acc[mf][nf][r] + bsum;
    }
  }
}

// ---------------- one LSTM timestep ----------------
// h_in/h_out/c transposed [dh][B]; xg_t: [B,4dh] fp32; x_out bf16 [B][ld]
__global__ __launch_bounds__(256) void lstm_step(const float* __restrict__ xg_t,
                                                 const float* __restrict__ Whh,
                                                 const float* __restrict__ h_in,
                                                 float* __restrict__ h_out, float* __restrict__ c_t,
                                                 unsigned short* __restrict__ x_out_t, int dh,
                                                 int ld) {
  int tid = threadIdx.x;
  int b = tid & 31;
  int gate = (tid >> 5) & 3;
  int ul = tid >> 7;
  int u = blockIdx.x * 2 + ul;
  int rowi = gate * dh + u;
  const float* wr = Whh + (size_t)rowi * dh;
  float acc = xg_t[b * (4 * dh) + rowi];
  for (int k = 0; k < dh; k += 2) {
    float2 wv = *(const float2*)&wr[k];
    acc += h_in[k * B_ + b] * wv.x;
    acc += h_in[(k + 1) * B_ + b] * wv.y;
  }
  __shared__ float red[2][4][32];
  red[ul][gate][b] = acc;
  __syncthreads();
  if (gate == 0) {
    float pi = red[ul][0][b], pf = red[ul][1][b], pg = red[ul][2][b], po = red[ul][3][b];
    float ig = sigmoidf_(pi), fg = sigmoidf_(pf), gg = tanhf(pg), og = sigmoidf_(po);
    float c = fg * c_t[u * B_ + b] + ig * gg;
    float h = og * tanhf(c);
    c_t[u * B_ + b] = c;
    h_out[u * B_ + b] = h;
    x_out_t[(size_t)b * ld + u] = f2bf(h);
  }
}

__global__ void init_hc(const float* __restrict__ h0, const float* __restrict__ c0,
                        float* __restrict__ h_t, float* __restrict__ c_t, int dh) {
  int i = blockIdx.x * blockDim.x + threadIdx.x;
  if (i >= dh * B_) return;
  int b = i / dh, u = i % dh;
  h_t[u * B_ + b] = h0[i];
  c_t[u * B_ + b] = c0[i];
}

__global__ void writeout_hc(const float* __restrict__ h_t, const float* __restrict__ c_t,
                            float* __restrict__ out_h, float* __restrict__ out_c, int dh) {
  int i = blockIdx.x * blockDim.x + threadIdx.x;
  if (i >= dh * B_) return;
  int b = i / dh, u = i % dh;
  out_h[i] = h_t[u * B_ + b];
  out_c[i] = c_t[u * B_ + b];
}

extern "C" void kernel_launch(void* const* d_in, const int* in_sizes, int n_in, void* d_out,
                              int out_size, void* d_ws, size_t ws_size, hipStream_t stream) {
  const int* input = (const int*)d_in[0];
  const float* emb_W = (const float*)d_in[1];
  const float* final_b = (const float*)d_in[2];

  struct L {
    const float *Wih, *Whh, *bih, *bhh, *h0, *c0;
    int din, dh;
  };
  L ls[3];
  ls[0] = {(const float*)d_in[3],  (const float*)d_in[4],  (const float*)d_in[5],
           (const float*)d_in[6],  (const float*)d_in[7],  (const float*)d_in[8],  400, 1150};
  ls[1] = {(const float*)d_in[9],  (const float*)d_in[10], (const float*)d_in[11],
           (const float*)d_in[12], (const float*)d_in[13], (const float*)d_in[14], 1150, 1150};
  ls[2] = {(const float*)d_in[15], (const float*)d_in[16], (const float*)d_in[17],
           (const float*)d_in[18], (const float*)d_in[19], (const float*)d_in[20], 1150, 400};

  // ---- workspace layout ----
  float* fw = (float*)d_ws;
  float* xg = fw;                      // 4096*4600 fp32
  float* hbuf0 = xg + (size_t)4096 * 4600;
  float* hbuf1 = hbuf0 + 1150 * 32;
  float* cbuf = hbuf1 + 1150 * 32;
  unsigned short* us = (unsigned short*)(cbuf + 1150 * 32);
  unsigned short* embbf = us;                         // [33280][416]
  unsigned short* w0 = embbf + (size_t)33280 * 416;   // [4608][416]
  unsigned short* w1 = w0 + (size_t)4608 * 416;       // [4608][1152]
  unsigned short* w2 = w1 + (size_t)4608 * 1152;      // [1664][1152]
  unsigned short* xa0 = w2 + (size_t)1664 * 1152;     // [4096][416]  (embed in, L2 out)
  unsigned short* xa1 = xa0 + (size_t)4096 * 416;     // [4096][1152] (L0 out)
  unsigned short* xa2 = xa1 + (size_t)4096 * 1152;    // [4096][1152] (L1 out)
  float* out = (float*)d_out;

  // ---- weight conversions (every call; deterministic) ----
  {
    long tot = (long)33280 * 416;
    convW<<<(unsigned)((tot + 255) / 256), 256, 0, stream>>>(emb_W, embbf, V_, E_, 416, tot);
  }
  {
    long tot = (long)4608 * 416;
    convW<<<(unsigned)((tot + 255) / 256), 256, 0, stream>>>(ls[0].Wih, w0, 4600, 400, 416, tot);
  }
  {
    long tot = (long)4608 * 1152;
    convW<<<(unsigned)((tot + 255) / 256), 256, 0, stream>>>(ls[1].Wih, w1, 4600, 1150, 1152, tot);
  }
  {
    long tot = (long)1664 * 1152;
    convW<<<(unsigned)((tot + 255) / 256), 256, 0, stream>>>(ls[2].Wih, w2, 1600, 1150, 1152, tot);
  }

  // embedding -> xa0 bf16 padded
  embed_kernel<<<(T_ * B_ * 416 + 255) / 256, 256, 0, stream>>>(input, emb_W, xa0);
  // zero pad cols of xa1/xa2 (cols 1150..1151)
  zpad<<<(T_ * B_ * 2 + 255) / 256, 256, 0, stream>>>(xa1, 1152, 1150);
  zpad<<<(T_ * B_ * 2 + 255) / 256, 256, 0, stream>>>(xa2, 1152, 1150);

  const unsigned short* Abufs[3] = {xa0, xa1, xa2};
  unsigned short* Obufs[3] = {xa1, xa2, xa0};
  const unsigned short* Wbufs[3] = {w0, w1, w2};
  const int Kps[3] = {416, 1152, 1152};
  const int N4s[3] = {4600, 4600, 1600};
  const int Ntiles[3] = {36, 36, 13};
  const int olds[3] = {1152, 1152, 416};

  long outOff = (long)T_ * B_ * V_;
  for (int l = 0; l < 3; ++l) {
    int dh = ls[l].dh, N4 = N4s[l];
    dim3 g(Ntiles[l], 4096 / 128);
    gemm_bf16<<<g, 256, 0, stream>>>(Abufs[l], Wbufs[l], ls[l].bih, ls[l].bhh, xg, 4096, Kps[l],
                                     N4, N4);
    init_hc<<<(dh * B_ + 255) / 256, 256, 0, stream>>>(ls[l].h0, ls[l].c0, hbuf0, cbuf, dh);
    for (int t = 0; t < T_; ++t) {
      const float* hin = (t & 1) ? hbuf1 : hbuf0;
      float* hout = (t & 1) ? hbuf0 : hbuf1;
      lstm_step<<<dh / 2, 256, 0, stream>>>(xg + (long)t * B_ * N4, ls[l].Whh, hin, hout, cbuf,
                                            Obufs[l] + (long)t * B_ * olds[l], dh, olds[l]);
    }
    writeout_hc<<<(dh * B_ + 255) / 256, 256, 0, stream>>>(hbuf0, cbuf, out + outOff,
                                                           out + outOff + B_ * dh, dh);
    outOff += 2L * B_ * dh;
  }

  // tied decoder: logits[4096, 33278] = x3 @ emb^T + final_b
  dim3 gd(260, 4096 / 128);
  gemm_bf16<<<gd, 256, 0, stream>>>(xa0, embbf, final_b, nullptr, out, 4096, 416, V_, V_);
}

// Round 3
// 15462.474 us; speedup vs baseline: 3.0855x; 2.7524x over previous
//
#include <hip/hip_runtime.h>
#include <math.h>

#define T_ 128
#define B_ 32
#define V_ 33278
#define E_ 400

typedef __bf16 bf16x8 __attribute__((ext_vector_type(8)));
typedef float f32x4 __attribute__((ext_vector_type(4)));

__device__ __forceinline__ float sigmoidf_(float x) { return 1.0f / (1.0f + expf(-x)); }

__device__ __forceinline__ unsigned short f2bf(float f) {
  unsigned u = __float_as_uint(f);
  unsigned lsb = (u >> 16) & 1;
  return (unsigned short)((u + 0x7FFFu + lsb) >> 16);
}

__device__ __forceinline__ void gload16(const unsigned short* g, unsigned short* l) {
  __builtin_amdgcn_global_load_lds((const __attribute__((address_space(1))) void*)g,
                                   (__attribute__((address_space(3))) void*)l, 16, 0, 0);
}

// ---------------- embedding gather -> bf16 padded [T*B][416] ----------------
__global__ void embed_kernel(const int* __restrict__ idx, const float* __restrict__ W,
                             unsigned short* __restrict__ x) {
  int i = blockIdx.x * blockDim.x + threadIdx.x;
  if (i >= T_ * B_ * 416) return;
  int k = i % 416;
  int tb = i / 416;
  x[i] = (k < E_) ? f2bf(W[(size_t)idx[tb] * E_ + k]) : 0;
}

// ---------------- fp32 -> bf16 weight conversion with padding ----------------
__global__ void convW(const float* __restrict__ in, unsigned short* __restrict__ out, int N, int K,
                      int Kp, long total) {
  long i = (long)blockIdx.x * blockDim.x + threadIdx.x;
  if (i >= total) return;
  int k = (int)(i % Kp);
  long n = i / Kp;
  out[i] = (n < N && k < K) ? f2bf(in[n * (long)K + k]) : 0;
}

// ---------------- bf16 MFMA GEMM: C[M,N] = A[M,Kp] * B[N,Kp]^T + bias ----------------
// Epilogue column remap (gateN>0): col = n + (n/gateN)*(gatePad-gateN)  (gate-padded xg layout)
__global__ __launch_bounds__(256) void gemm_bf16(const unsigned short* __restrict__ A,
                                                 const unsigned short* __restrict__ B,
                                                 const float* __restrict__ bias0,
                                                 const float* __restrict__ bias1,
                                                 float* __restrict__ C, int M, int Kp, int ldc,
                                                 int realN, int gateN, int gatePad) {
  __shared__ __align__(16) unsigned short lsA[4 * 128 * 8];
  __shared__ __align__(16) unsigned short lsB[4 * 128 * 8];
  const int tid = threadIdx.x;
  const int lane = tid & 63;
  const int w = tid >> 6;
  const int wm = (w >> 1) * 64;
  const int wn = (w & 1) * 64;
  const int lr = lane & 15;
  const int kq = lane >> 4;
  const int m0 = blockIdx.y * 128;
  const int n0 = blockIdx.x * 128;

  f32x4 acc[4][4] = {};

  const int kiters = Kp >> 5;
  for (int kt = 0; kt < kiters; ++kt) {
    const int k0 = kt << 5;
#pragma unroll
    for (int q = 0; q < 2; ++q) {
      int s = w + q * 4;
      int kc = s >> 1, rb = (s & 1) * 64;
      gload16(A + (size_t)(m0 + rb + lane) * Kp + k0 + kc * 8, lsA + s * 512);
      gload16(B + (size_t)(n0 + rb + lane) * Kp + k0 + kc * 8, lsB + s * 512);
    }
    __syncthreads();

    bf16x8 af[4], bf[4];
#pragma unroll
    for (int mf = 0; mf < 4; ++mf)
      af[mf] = *(const bf16x8*)&lsA[(kq * 128 + wm + mf * 16 + lr) * 8];
#pragma unroll
    for (int nf = 0; nf < 4; ++nf)
      bf[nf] = *(const bf16x8*)&lsB[(kq * 128 + wn + nf * 16 + lr) * 8];
#pragma unroll
    for (int mf = 0; mf < 4; ++mf)
#pragma unroll
      for (int nf = 0; nf < 4; ++nf)
        acc[mf][nf] = __builtin_amdgcn_mfma_f32_16x16x32_bf16(af[mf], bf[nf], acc[mf][nf], 0, 0, 0);
    __syncthreads();
  }

#pragma unroll
  for (int nf = 0; nf < 4; ++nf) {
    int n = n0 + wn + nf * 16 + lr;
    if (n >= realN) continue;
    float bsum = 0.0f;
    if (bias0) bsum += bias0[n];
    if (bias1) bsum += bias1[n];
    int col = n;
    if (gateN > 0) {
      int gg = (n >= gateN) + (n >= 2 * gateN) + (n >= 3 * gateN);
      col = n + gg * (gatePad - gateN);
    }
#pragma unroll
    for (int mf = 0; mf < 4; ++mf) {
      int mbase = m0 + wm + mf * 16 + kq * 4;
#pragma unroll
      for (int r = 0; r < 4; ++r) C[(size_t)(mbase + r) * ldc + col] = acc[mf][nf][r] + bsum;
    }
  }
}

// ---------------- device-scope global barrier ----------------
__device__ __forceinline__ void gbar(int* cnt, int* gen, int NB) {
  __threadfence();
  __syncthreads();
  if (threadIdx.x == 0) {
    int g = __hip_atomic_load(gen, __ATOMIC_RELAXED, __HIP_MEMORY_SCOPE_AGENT);
    int old = __hip_atomic_fetch_add(cnt, 1, __ATOMIC_ACQ_REL, __HIP_MEMORY_SCOPE_AGENT);
    if (old == NB - 1) {
      __hip_atomic_store(cnt, 0, __ATOMIC_RELAXED, __HIP_MEMORY_SCOPE_AGENT);
      __hip_atomic_fetch_add(gen, 1, __ATOMIC_RELEASE, __HIP_MEMORY_SCOPE_AGENT);
    } else {
      while (__hip_atomic_load(gen, __ATOMIC_RELAXED, __HIP_MEMORY_SCOPE_AGENT) == g)
        __builtin_amdgcn_s_sleep(2);
    }
  }
  __syncthreads();
  __threadfence();
}

// ---------------- persistent LSTM recurrence (one launch per layer) ----------------
// Block b owns units [4b, 4b+4) = 16 Whh rows (gate-major: m = g*4+ul), W in VGPRs as
// MFMA A-frags. h-chain xa: [(1+T)*32][KP] bf16; row-block 0 = h0, block t+1 = step-t out.
// xg: gate-padded fp32 [T*32][4*KP]. c stays in registers (1 value/thread).
template <int KT>
__global__ __launch_bounds__(128) void lstm_persist(const float* __restrict__ xg,
                                                    const float* __restrict__ Whh,
                                                    const float* __restrict__ h0,
                                                    const float* __restrict__ c0,
                                                    unsigned short* __restrict__ xa,
                                                    float* __restrict__ out_h,
                                                    float* __restrict__ out_c, int dh, int NB,
                                                    int* __restrict__ bar) {
  constexpr int KP = KT * 32;
  const int XG = 4 * KP;
  const int tid = threadIdx.x;
  const int lane = tid & 63;
  const int nt = tid >> 6;  // wave = N-tile (batch 16-half)
  const int u0 = blockIdx.x * 4;
  const int lm = lane & 15;               // A/B row-within-tile
  const int ga = lm >> 2, ula = lm & 3;   // A-row -> (gate, unit-local)
  const int kq = lane >> 4;               // k-chunk / C-row group
  const int nb = nt * 16 + lm;            // batch index for B/C cols

  // ---- Whh fragments -> registers (bf16), loaded once ----
  bf16x8 aw[KT];
  {
    const bool vu = (u0 + ula) < dh;
    const size_t rbase = (size_t)(ga * dh + u0 + ula) * dh;
#pragma unroll
    for (int kt = 0; kt < KT; ++kt) {
      bf16x8 v;
#pragma unroll
      for (int j = 0; j < 8; ++j) {
        int k = kt * 32 + kq * 8 + j;
        float f = (vu && k < dh) ? Whh[rbase + k] : 0.0f;
        v[j] = (__bf16)f;
      }
      aw[kt] = v;
    }
  }

  // ---- c-state: one (unit, batch) pair per thread ----
  const int uc = tid >> 5;  // 0..3
  const int nc = tid & 31;
  const bool vuc = (u0 + uc) < dh;
  float creg = vuc ? c0[nc * dh + u0 + uc] : 0.0f;
  {
    float h0v = vuc ? h0[nc * dh + u0 + uc] : 0.0f;
    xa[(size_t)nc * KP + u0 + uc] = vuc ? f2bf(h0v) : (unsigned short)0;
  }
  gbar(bar, bar + 1, NB);

  __shared__ float pre[2][4][4][16];  // [wave][gate][unit][batch-col]

  for (int t = 0; t < T_; ++t) {
    // C-init from xg (aligned float4: this lane's gate kq, units u0..u0+3, batch nb)
    f32x4 acc = *(const f32x4*)&xg[(size_t)(t * 32 + nb) * XG + kq * KP + u0];
    const unsigned short* hr = xa + (size_t)(t * 32 + nb) * KP;
#pragma unroll
    for (int kt = 0; kt < KT; ++kt) {
      bf16x8 bh = *(const bf16x8*)&hr[kt * 32 + kq * 8];
      acc = __builtin_amdgcn_mfma_f32_16x16x32_bf16(aw[kt], bh, acc, 0, 0, 0);
    }
#pragma unroll
    for (int r = 0; r < 4; ++r) pre[nt][kq][r][lm] = acc[r];
    __syncthreads();
    float pi = pre[nc >> 4][0][uc][nc & 15];
    float pf = pre[nc >> 4][1][uc][nc & 15];
    float pg = pre[nc >> 4][2][uc][nc & 15];
    float po = pre[nc >> 4][3][uc][nc & 15];
    float cn = sigmoidf_(pf) * creg + sigmoidf_(pi) * tanhf(pg);
    float hn = sigmoidf_(po) * tanhf(cn);
    creg = cn;
    xa[(size_t)(32 + t * 32 + nc) * KP + u0 + uc] = vuc ? f2bf(hn) : (unsigned short)0;
    if (t == T_ - 1 && vuc) {
      out_h[nc * dh + u0 + uc] = hn;
      out_c[nc * dh + u0 + uc] = cn;
    }
    gbar(bar, bar + 1, NB);
  }
}

extern "C" void kernel_launch(void* const* d_in, const int* in_sizes, int n_in, void* d_out,
                              int out_size, void* d_ws, size_t ws_size, hipStream_t stream) {
  const int* input = (const int*)d_in[0];
  const float* emb_W = (const float*)d_in[1];
  const float* final_b = (const float*)d_in[2];

  struct L {
    const float *Wih, *Whh, *bih, *bhh, *h0, *c0;
  };
  L ls[3];
  ls[0] = {(const float*)d_in[3],  (const float*)d_in[4],  (const float*)d_in[5],
           (const float*)d_in[6],  (const float*)d_in[7],  (const float*)d_in[8]};
  ls[1] = {(const float*)d_in[9],  (const float*)d_in[10], (const float*)d_in[11],
           (const float*)d_in[12], (const float*)d_in[13], (const float*)d_in[14]};
  ls[2] = {(const float*)d_in[15], (const float*)d_in[16], (const float*)d_in[17],
           (const float*)d_in[18], (const float*)d_in[19], (const float*)d_in[20]};

  // ---- workspace layout ----
  int* bar = (int*)d_ws;                       // 128 B (memset each call)
  float* xg = (float*)d_ws + 32;               // [4096][4608] fp32
  unsigned short* us = (unsigned short*)(xg + (size_t)4096 * 4608);
  unsigned short* embbf = us;                        // [33280][416]
  unsigned short* w0 = embbf + (size_t)33280 * 416;  // [4608][416]
  unsigned short* w1 = w0 + (size_t)4608 * 416;      // [4608][1152]
  unsigned short* w2 = w1 + (size_t)4608 * 1152;     // [1664][1152]
  unsigned short* xa1 = w2 + (size_t)1664 * 1152;    // [4128][1152] (L0 h-chain / L1 in)
  unsigned short* xa2 = xa1 + (size_t)4128 * 1152;   // [4128][1152] (L1 h-chain / L2 in)
  unsigned short* xa3 = xa2 + (size_t)4128 * 1152;   // [4128][416]  (embed in, later L2 h-chain)
  float* out = (float*)d_out;

  hipMemsetAsync(bar, 0, 128, stream);

  // ---- conversions ----
  {
    long tot = (long)33280 * 416;
    convW<<<(unsigned)((tot + 255) / 256), 256, 0, stream>>>(emb_W, embbf, V_, E_, 416, tot);
  }
  {
    long tot = (long)4608 * 416;
    convW<<<(unsigned)((tot + 255) / 256), 256, 0, stream>>>(ls[0].Wih, w0, 4600, 400, 416, tot);
  }
  {
    long tot = (long)4608 * 1152;
    convW<<<(unsigned)((tot + 255) / 256), 256, 0, stream>>>(ls[1].Wih, w1, 4600, 1150, 1152, tot);
  }
  {
    long tot = (long)1664 * 1152;
    convW<<<(unsigned)((tot + 255) / 256), 256, 0, stream>>>(ls[2].Wih, w2, 1600, 1150, 1152, tot);
  }
  embed_kernel<<<(T_ * B_ * 416 + 255) / 256, 256, 0, stream>>>(input, emb_W, xa3);

  long o = (long)T_ * B_ * V_;
  float* oh0 = out + o;        float* oc0 = oh0 + 32 * 1150;
  float* oh1 = oc0 + 32 * 1150; float* oc1 = oh1 + 32 * 1150;
  float* oh2 = oc1 + 32 * 1150; float* oc2 = oh2 + 32 * 400;

  // ---- layer 0 ----
  gemm_bf16<<<dim3(36, 32), 256, 0, stream>>>(xa3, w0, ls[0].bih, ls[0].bhh, xg, 4096, 416, 4608,
                                              4600, 1150, 1152);
  lstm_persist<36><<<288, 128, 0, stream>>>(xg, ls[0].Whh, ls[0].h0, ls[0].c0, xa1, oh0, oc0, 1150,
                                            288, bar);
  // ---- layer 1 ----
  gemm_bf16<<<dim3(36, 32), 256, 0, stream>>>(xa1 + (size_t)32 * 1152, w1, ls[1].bih, ls[1].bhh,
                                              xg, 4096, 1152, 4608, 4600, 1150, 1152);
  lstm_persist<36><<<288, 128, 0, stream>>>(xg, ls[1].Whh, ls[1].h0, ls[1].c0, xa2, oh1, oc1, 1150,
                                            288, bar);
  // ---- layer 2 ----
  gemm_bf16<<<dim3(13, 32), 256, 0, stream>>>(xa2 + (size_t)32 * 1152, w2, ls[2].bih, ls[2].bhh,
                                              xg, 4096, 1152, 1664, 1600, 400, 416);
  lstm_persist<13><<<104, 128, 0, stream>>>(xg, ls[2].Whh, ls[2].h0, ls[2].c0, xa3, oh2, oc2, 400,
                                            104, bar);
  // ---- tied decoder ----
  gemm_bf16<<<dim3(260, 32), 256, 0, stream>>>(xa3 + (size_t)32 * 416, embbf, final_b, nullptr,
                                               out, 4096, 416, V_, V_, 0, 0);
}

// Round 4
// 2701.463 us; speedup vs baseline: 17.6605x; 5.7237x over previous
//
#include <hip/hip_runtime.h>
#include <math.h>

#define T_ 128
#define B_ 32
#define V_ 33278
#define E_ 400

typedef __bf16 bf16x8 __attribute__((ext_vector_type(8)));
typedef float f32x4 __attribute__((ext_vector_type(4)));

__device__ __forceinline__ float sigmoidf_(float x) { return 1.0f / (1.0f + expf(-x)); }

__device__ __forceinline__ unsigned short f2bf(float f) {
  unsigned u = __float_as_uint(f);
  unsigned lsb = (u >> 16) & 1;
  return (unsigned short)((u + 0x7FFFu + lsb) >> 16);
}

__device__ __forceinline__ void gload16(const unsigned short* g, unsigned short* l) {
  __builtin_amdgcn_global_load_lds((const __attribute__((address_space(1))) void*)g,
                                   (__attribute__((address_space(3))) void*)l, 16, 0, 0);
}

// ---------------- embedding gather -> bf16 padded [T*B][416] ----------------
__global__ void embed_kernel(const int* __restrict__ idx, const float* __restrict__ W,
                             unsigned short* __restrict__ x) {
  int i = blockIdx.x * blockDim.x + threadIdx.x;
  if (i >= T_ * B_ * 416) return;
  int k = i % 416;
  int tb = i / 416;
  x[i] = (k < E_) ? f2bf(W[(size_t)idx[tb] * E_ + k]) : 0;
}

// ---------------- fp32 -> bf16 weight conversion with padding ----------------
__global__ void convW(const float* __restrict__ in, unsigned short* __restrict__ out, int N, int K,
                      int Kp, long total) {
  long i = (long)blockIdx.x * blockDim.x + threadIdx.x;
  if (i >= total) return;
  int k = (int)(i % Kp);
  long n = i / Kp;
  out[i] = (n < N && k < K) ? f2bf(in[n * (long)K + k]) : 0;
}

// ---------------- bf16 MFMA GEMM: C[M,N] = A[M,Kp] * B[N,Kp]^T + bias ----------------
// Epilogue column remap (gateN>0): col = n + (n/gateN)*(gatePad-gateN)  (gate-padded xg layout)
__global__ __launch_bounds__(256) void gemm_bf16(const unsigned short* __restrict__ A,
                                                 const unsigned short* __restrict__ B,
                                                 const float* __restrict__ bias0,
                                                 const float* __restrict__ bias1,
                                                 float* __restrict__ C, int M, int Kp, int ldc,
                                                 int realN, int gateN, int gatePad) {
  __shared__ __align__(16) unsigned short lsA[4 * 128 * 8];
  __shared__ __align__(16) unsigned short lsB[4 * 128 * 8];
  const int tid = threadIdx.x;
  const int lane = tid & 63;
  const int w = tid >> 6;
  const int wm = (w >> 1) * 64;
  const int wn = (w & 1) * 64;
  const int lr = lane & 15;
  const int kq = lane >> 4;
  const int m0 = blockIdx.y * 128;
  const int n0 = blockIdx.x * 128;

  f32x4 acc[4][4] = {};

  const int kiters = Kp >> 5;
  for (int kt = 0; kt < kiters; ++kt) {
    const int k0 = kt << 5;
#pragma unroll
    for (int q = 0; q < 2; ++q) {
      int s = w + q * 4;
      int kc = s >> 1, rb = (s & 1) * 64;
      gload16(A + (size_t)(m0 + rb + lane) * Kp + k0 + kc * 8, lsA + s * 512);
      gload16(B + (size_t)(n0 + rb + lane) * Kp + k0 + kc * 8, lsB + s * 512);
    }
    __syncthreads();

    bf16x8 af[4], bf[4];
#pragma unroll
    for (int mf = 0; mf < 4; ++mf)
      af[mf] = *(const bf16x8*)&lsA[(kq * 128 + wm + mf * 16 + lr) * 8];
#pragma unroll
    for (int nf = 0; nf < 4; ++nf)
      bf[nf] = *(const bf16x8*)&lsB[(kq * 128 + wn + nf * 16 + lr) * 8];
#pragma unroll
    for (int mf = 0; mf < 4; ++mf)
#pragma unroll
      for (int nf = 0; nf < 4; ++nf)
        acc[mf][nf] = __builtin_amdgcn_mfma_f32_16x16x32_bf16(af[mf], bf[nf], acc[mf][nf], 0, 0, 0);
    __syncthreads();
  }

#pragma unroll
  for (int nf = 0; nf < 4; ++nf) {
    int n = n0 + wn + nf * 16 + lr;
    if (n >= realN) continue;
    float bsum = 0.0f;
    if (bias0) bsum += bias0[n];
    if (bias1) bsum += bias1[n];
    int col = n;
    if (gateN > 0) {
      int gg = (n >= gateN) + (n >= 2 * gateN) + (n >= 3 * gateN);
      col = n + gg * (gatePad - gateN);
    }
#pragma unroll
    for (int mf = 0; mf < 4; ++mf) {
      int mbase = m0 + wm + mf * 16 + kq * 4;
#pragma unroll
      for (int r = 0; r < 4; ++r) C[(size_t)(mbase + r) * ldc + col] = acc[mf][nf][r] + bsum;
    }
  }
}

// ---------------- persistent LSTM recurrence, flag-barrier version ----------------
// Block bid: half = bid&1 (batch 16-half), U0 = (bid>>1)*32 (unit group).
// 512 threads = 8 waves; wave w = units U0+w*4..+3 (x 4 gates) x 16 batches.
// Whh A-frags in VGPRs. h-chain xa [(1+T)*32][KP] bf16, accessed ONLY via
// agent-scope (L2-bypass) atomics inside this kernel. Per-block flag on its
// own 64B line; no fences, no atomic RMW.
template <int KT>
__global__ __launch_bounds__(512, 1) void lstm_persist(
    const float* __restrict__ xg, const float* __restrict__ Whh, const float* __restrict__ h0,
    const float* __restrict__ c0, unsigned short* __restrict__ xa, float* __restrict__ out_h,
    float* __restrict__ out_c, int dh, int NB, int* __restrict__ flags) {
  constexpr int KP = KT * 32;
  constexpr int KPP = KP + 8;      // LDS row pad
  constexpr int XG = 4 * KP;       // xg row stride (gate-padded)
  constexpr int CPR = KP / 8;      // 16B chunks per h-row
  constexpr int NCH = 16 * CPR;    // staging chunks per step
  constexpr int NIT = (NCH + 511) / 512;

  __shared__ __align__(16) unsigned short hbuf[16 * KPP];
  __shared__ float pre[4 * 16 * 33];  // [gate][batch][unit(+pad)]

  const int tid = threadIdx.x;
  const int lane = tid & 63;
  const int w = tid >> 6;  // wave = unit quad
  const int lm = lane & 15;
  const int kq = lane >> 4;
  const int bid = blockIdx.x;
  const int half = bid & 1;
  const int U0 = (bid >> 1) * 32;
  const int nb = half * 16 + lm;  // global batch for MFMA B/C col

  // ---- Whh -> A-fragments (once) ----
  bf16x8 aw[KT];
  {
    const int ga = lm >> 2, ula = lm & 3;
    const int un = U0 + w * 4 + ula;
    const bool vu = un < dh;
    const float* wr = Whh + (size_t)(ga * dh + (vu ? un : 0)) * dh;
#pragma unroll
    for (int kt = 0; kt < KT; ++kt) {
      bf16x8 v;
#pragma unroll
      for (int j = 0; j < 8; ++j) {
        int k = kt * 32 + kq * 8 + j;
        float f = (vu && k < dh) ? wr[k] : 0.0f;
        v[j] = (__bf16)f;
      }
      aw[kt] = v;
    }
  }

  // ---- per-thread cell state: thread = (uc = tid&31, ncl = tid>>5) ----
  const int uc = tid & 31, ncl = tid >> 5;
  const int un2 = U0 + uc;
  const int gb = half * 16 + ncl;  // global batch
  const bool vu2 = un2 < dh;
  float creg = vu2 ? c0[gb * dh + un2] : 0.0f;

  // ---- publish h0 (row 0), pair-packed u32 agent stores ----
  {
    unsigned hv = vu2 ? (unsigned)f2bf(h0[gb * dh + (vu2 ? un2 : 0)]) : 0u;
    unsigned other = (unsigned)__shfl_xor((int)hv, 1);
    if (!(tid & 1)) {
      unsigned pack = (hv & 0xffffu) | (other << 16);
      __hip_atomic_store((unsigned*)(xa + (size_t)gb * KP + un2), pack, __ATOMIC_RELAXED,
                         __HIP_MEMORY_SCOPE_AGENT);
    }
  }
  asm volatile("s_waitcnt vmcnt(0)" ::: "memory");
  __syncthreads();
  if (tid == 0)
    __hip_atomic_store(&flags[bid * 16], 1, __ATOMIC_RELAXED, __HIP_MEMORY_SCOPE_AGENT);

  for (int t = 0; t < T_; ++t) {
    // xg C-init prefetch (normal load; latency hides under the poll)
    f32x4 cinit = *(const f32x4*)&xg[(size_t)(t * 32 + nb) * XG + kq * KP + U0 + w * 4];

    // ---- flag poll: all NB flags >= t+1 ----
    {
      const int tgt = t + 1;
      const bool need = lane < NB;
      for (;;) {
        int v = need ? __hip_atomic_load(&flags[lane * 16], __ATOMIC_RELAXED,
                                         __HIP_MEMORY_SCOPE_AGENT)
                     : tgt;
        int v2 = (lane + 64 < NB) ? __hip_atomic_load(&flags[(lane + 64) * 16], __ATOMIC_RELAXED,
                                                      __HIP_MEMORY_SCOPE_AGENT)
                                  : tgt;
        if (__all(v >= tgt && v2 >= tgt)) break;
        __builtin_amdgcn_s_sleep(1);
      }
    }

    // ---- stage our half's h rows (row-block t) into LDS ----
    {
      unsigned d[NIT][4];
#pragma unroll
      for (int i = 0; i < NIT; ++i) {
        int c = tid + i * 512;
        if (c < NCH) {
          int row = c / CPR, col = c % CPR;
          unsigned* gp = (unsigned*)(xa + (size_t)(t * 32 + half * 16 + row) * KP + col * 8);
#pragma unroll
          for (int j = 0; j < 4; ++j)
            d[i][j] = __hip_atomic_load(gp + j, __ATOMIC_RELAXED, __HIP_MEMORY_SCOPE_AGENT);
        }
      }
#pragma unroll
      for (int i = 0; i < NIT; ++i) {
        int c = tid + i * 512;
        if (c < NCH) {
          int row = c / CPR, col = c % CPR;
          uint4 u = {d[i][0], d[i][1], d[i][2], d[i][3]};
          *(uint4*)((char*)hbuf + row * KPP * 2 + col * 16) = u;
        }
      }
    }
    __syncthreads();

    // ---- MFMA: pre-activations for this wave's 16 rows x 16 batches ----
    f32x4 acc0 = cinit;
    f32x4 acc1 = {0.0f, 0.0f, 0.0f, 0.0f};
#pragma unroll
    for (int kt = 0; kt < KT; kt += 2) {
      bf16x8 bh0 = *(const bf16x8*)&hbuf[lm * KPP + kt * 32 + kq * 8];
      acc0 = __builtin_amdgcn_mfma_f32_16x16x32_bf16(aw[kt], bh0, acc0, 0, 0, 0);
      if (kt + 1 < KT) {
        bf16x8 bh1 = *(const bf16x8*)&hbuf[lm * KPP + (kt + 1) * 32 + kq * 8];
        acc1 = __builtin_amdgcn_mfma_f32_16x16x32_bf16(aw[kt + 1], bh1, acc1, 0, 0, 0);
      }
    }
    // C/D: row m = kq*4+r -> gate kq, unit-local w*4+r; col = lm = batch
#pragma unroll
    for (int r = 0; r < 4; ++r) pre[(kq * 16 + lm) * 33 + w * 4 + r] = acc0[r] + acc1[r];
    __syncthreads();

    // ---- gate combine + cell update ----
    float pi = pre[(0 * 16 + ncl) * 33 + uc];
    float pf = pre[(1 * 16 + ncl) * 33 + uc];
    float pg = pre[(2 * 16 + ncl) * 33 + uc];
    float po = pre[(3 * 16 + ncl) * 33 + uc];
    float cn = sigmoidf_(pf) * creg + sigmoidf_(pi) * tanhf(pg);
    float hn = sigmoidf_(po) * tanhf(cn);
    creg = cn;
    unsigned hv = vu2 ? (unsigned)f2bf(hn) : 0u;
    unsigned other = (unsigned)__shfl_xor((int)hv, 1);
    if (!(tid & 1)) {
      unsigned pack = (hv & 0xffffu) | (other << 16);
      __hip_atomic_store((unsigned*)(xa + (size_t)((t + 1) * 32 + gb) * KP + un2), pack,
                         __ATOMIC_RELAXED, __HIP_MEMORY_SCOPE_AGENT);
    }
    if (t == T_ - 1 && vu2) {
      out_h[gb * dh + un2] = hn;
      out_c[gb * dh + un2] = cn;
    }
    asm volatile("s_waitcnt vmcnt(0)" ::: "memory");
    __syncthreads();
    if (tid == 0)
      __hip_atomic_store(&flags[bid * 16], t + 2, __ATOMIC_RELAXED, __HIP_MEMORY_SCOPE_AGENT);
  }
}

extern "C" void kernel_launch(void* const* d_in, const int* in_sizes, int n_in, void* d_out,
                              int out_size, void* d_ws, size_t ws_size, hipStream_t stream) {
  const int* input = (const int*)d_in[0];
  const float* emb_W = (const float*)d_in[1];
  const float* final_b = (const float*)d_in[2];

  struct L {
    const float *Wih, *Whh, *bih, *bhh, *h0, *c0;
  };
  L ls[3];
  ls[0] = {(const float*)d_in[3],  (const float*)d_in[4],  (const float*)d_in[5],
           (const float*)d_in[6],  (const float*)d_in[7],  (const float*)d_in[8]};
  ls[1] = {(const float*)d_in[9],  (const float*)d_in[10], (const float*)d_in[11],
           (const float*)d_in[12], (const float*)d_in[13], (const float*)d_in[14]};
  ls[2] = {(const float*)d_in[15], (const float*)d_in[16], (const float*)d_in[17],
           (const float*)d_in[18], (const float*)d_in[19], (const float*)d_in[20]};

  // ---- workspace layout ----
  char* base = (char*)d_ws;
  int* bar = (int*)base;  // 16KB: 3 layers x 72 flags x 64B lines
  float* xg = (float*)(base + 16384);               // [4096][4608] fp32
  unsigned short* us = (unsigned short*)(xg + (size_t)4096 * 4608);
  unsigned short* embbf = us;                        // [33280][416]
  unsigned short* w0 = embbf + (size_t)33280 * 416;  // [4608][416]
  unsigned short* w1 = w0 + (size_t)4608 * 416;      // [4608][1152]
  unsigned short* w2 = w1 + (size_t)4608 * 1152;     // [1664][1152]
  unsigned short* xa1 = w2 + (size_t)1664 * 1152;    // [4128][1152] L0 h-chain / L1 in
  unsigned short* xa2 = xa1 + (size_t)4128 * 1152;   // [4128][1152] L1 h-chain / L2 in
  unsigned short* xa3 = xa2 + (size_t)4128 * 1152;   // [4128][416]  embed in / L2 h-chain
  float* out = (float*)d_out;

  int* flags0 = bar;
  int* flags1 = bar + 72 * 16;
  int* flags2 = bar + 144 * 16;
  hipMemsetAsync(bar, 0, 16384, stream);

  // ---- conversions ----
  {
    long tot = (long)33280 * 416;
    convW<<<(unsigned)((tot + 255) / 256), 256, 0, stream>>>(emb_W, embbf, V_, E_, 416, tot);
  }
  {
    long tot = (long)4608 * 416;
    convW<<<(unsigned)((tot + 255) / 256), 256, 0, stream>>>(ls[0].Wih, w0, 4600, 400, 416, tot);
  }
  {
    long tot = (long)4608 * 1152;
    convW<<<(unsigned)((tot + 255) / 256), 256, 0, stream>>>(ls[1].Wih, w1, 4600, 1150, 1152, tot);
  }
  {
    long tot = (long)1664 * 1152;
    convW<<<(unsigned)((tot + 255) / 256), 256, 0, stream>>>(ls[2].Wih, w2, 1600, 1150, 1152, tot);
  }
  embed_kernel<<<(T_ * B_ * 416 + 255) / 256, 256, 0, stream>>>(input, emb_W, xa3);

  long o = (long)T_ * B_ * V_;
  float* oh0 = out + o;         float* oc0 = oh0 + 32 * 1150;
  float* oh1 = oc0 + 32 * 1150; float* oc1 = oh1 + 32 * 1150;
  float* oh2 = oc1 + 32 * 1150; float* oc2 = oh2 + 32 * 400;

  // ---- layer 0 ----
  gemm_bf16<<<dim3(36, 32), 256, 0, stream>>>(xa3, w0, ls[0].bih, ls[0].bhh, xg, 4096, 416, 4608,
                                              4600, 1150, 1152);
  lstm_persist<36><<<72, 512, 0, stream>>>(xg, ls[0].Whh, ls[0].h0, ls[0].c0, xa1, oh0, oc0, 1150,
                                           72, flags0);
  // ---- layer 1 ----
  gemm_bf16<<<dim3(36, 32), 256, 0, stream>>>(xa1 + (size_t)32 * 1152, w1, ls[1].bih, ls[1].bhh,
                                              xg, 4096, 1152, 4608, 4600, 1150, 1152);
  lstm_persist<36><<<72, 512, 0, stream>>>(xg, ls[1].Whh, ls[1].h0, ls[1].c0, xa2, oh1, oc1, 1150,
                                           72, flags1);
  // ---- layer 2 ----
  gemm_bf16<<<dim3(13, 32), 256, 0, stream>>>(xa2 + (size_t)32 * 1152, w2, ls[2].bih, ls[2].bhh,
                                              xg, 4096, 1152, 1664, 1600, 400, 416);
  lstm_persist<13><<<26, 512, 0, stream>>>(xg, ls[2].Whh, ls[2].h0, ls[2].c0, xa3, oh2, oc2, 400,
                                           26, flags2);
  // ---- tied decoder ----
  gemm_bf16<<<dim3(260, 32), 256, 0, stream>>>(xa3 + (size_t)32 * 416, embbf, final_b, nullptr,
                                               out, 4096, 416, V_, V_, 0, 0);
}

// Round 5
// 2200.386 us; speedup vs baseline: 21.6821x; 1.2277x over previous
//
#include <hip/hip_runtime.h>
#include <math.h>

#define T_ 128
#define B_ 32
#define V_ 33278
#define E_ 400

typedef __bf16 bf16x8 __attribute__((ext_vector_type(8)));
typedef float f32x4 __attribute__((ext_vector_type(4)));

__device__ __forceinline__ float exp2f_(float x) {
  float r;
  asm("v_exp_f32 %0, %1" : "=v"(r) : "v"(x));
  return r;
}
__device__ __forceinline__ float rcpf_(float x) {
  float r;
  asm("v_rcp_f32 %0, %1" : "=v"(r) : "v"(x));
  return r;
}
__device__ __forceinline__ float sigf_(float x) { return rcpf_(1.0f + exp2f_(-1.44269504f * x)); }
__device__ __forceinline__ float tanhf_(float x) {
  float t = exp2f_(2.88539008f * x);
  return 1.0f - 2.0f * rcpf_(t + 1.0f);
}

__device__ __forceinline__ unsigned short f2bf(float f) {
  unsigned u = __float_as_uint(f);
  unsigned lsb = (u >> 16) & 1;
  return (unsigned short)((u + 0x7FFFu + lsb) >> 16);
}

__device__ __forceinline__ void gload16(const unsigned short* g, unsigned short* l) {
  __builtin_amdgcn_global_load_lds((const __attribute__((address_space(1))) void*)g,
                                   (__attribute__((address_space(3))) void*)l, 16, 0, 0);
}

// ---------------- embedding gather -> bf16 padded [T*B][416] ----------------
__global__ void embed_kernel(const int* __restrict__ idx, const float* __restrict__ W,
                             unsigned short* __restrict__ x) {
  int i = blockIdx.x * blockDim.x + threadIdx.x;
  if (i >= T_ * B_ * 416) return;
  int k = i % 416;
  int tb = i / 416;
  x[i] = (k < E_) ? f2bf(W[(size_t)idx[tb] * E_ + k]) : 0;
}

// ---------------- fp32 -> bf16 weight conversion with padding ----------------
__global__ void convW(const float* __restrict__ in, unsigned short* __restrict__ out, int N, int K,
                      int Kp, long total) {
  long i = (long)blockIdx.x * blockDim.x + threadIdx.x;
  if (i >= total) return;
  int k = (int)(i % Kp);
  long n = i / Kp;
  out[i] = (n < N && k < K) ? f2bf(in[n * (long)K + k]) : 0;
}

// ---------------- bf16 MFMA GEMM: C[M,N] = A[M,Kp] * B[N,Kp]^T + bias ----------------
__global__ __launch_bounds__(256) void gemm_bf16(const unsigned short* __restrict__ A,
                                                 const unsigned short* __restrict__ B,
                                                 const float* __restrict__ bias0,
                                                 const float* __restrict__ bias1,
                                                 float* __restrict__ C, int M, int Kp, int ldc,
                                                 int realN, int gateN, int gatePad) {
  __shared__ __align__(16) unsigned short lsA[4 * 128 * 8];
  __shared__ __align__(16) unsigned short lsB[4 * 128 * 8];
  const int tid = threadIdx.x;
  const int lane = tid & 63;
  const int w = tid >> 6;
  const int wm = (w >> 1) * 64;
  const int wn = (w & 1) * 64;
  const int lr = lane & 15;
  const int kq = lane >> 4;
  const int m0 = blockIdx.y * 128;
  const int n0 = blockIdx.x * 128;

  f32x4 acc[4][4] = {};

  const int kiters = Kp >> 5;
  for (int kt = 0; kt < kiters; ++kt) {
    const int k0 = kt << 5;
#pragma unroll
    for (int q = 0; q < 2; ++q) {
      int s = w + q * 4;
      int kc = s >> 1, rb = (s & 1) * 64;
      gload16(A + (size_t)(m0 + rb + lane) * Kp + k0 + kc * 8, lsA + s * 512);
      gload16(B + (size_t)(n0 + rb + lane) * Kp + k0 + kc * 8, lsB + s * 512);
    }
    __syncthreads();

    bf16x8 af[4], bf[4];
#pragma unroll
    for (int mf = 0; mf < 4; ++mf)
      af[mf] = *(const bf16x8*)&lsA[(kq * 128 + wm + mf * 16 + lr) * 8];
#pragma unroll
    for (int nf = 0; nf < 4; ++nf)
      bf[nf] = *(const bf16x8*)&lsB[(kq * 128 + wn + nf * 16 + lr) * 8];
#pragma unroll
    for (int mf = 0; mf < 4; ++mf)
#pragma unroll
      for (int nf = 0; nf < 4; ++nf)
        acc[mf][nf] = __builtin_amdgcn_mfma_f32_16x16x32_bf16(af[mf], bf[nf], acc[mf][nf], 0, 0, 0);
    __syncthreads();
  }

#pragma unroll
  for (int nf = 0; nf < 4; ++nf) {
    int n = n0 + wn + nf * 16 + lr;
    if (n >= realN) continue;
    float bsum = 0.0f;
    if (bias0) bsum += bias0[n];
    if (bias1) bsum += bias1[n];
    int col = n;
    if (gateN > 0) {
      int gg = (n >= gateN) + (n >= 2 * gateN) + (n >= 3 * gateN);
      col = n + gg * (gatePad - gateN);
    }
#pragma unroll
    for (int mf = 0; mf < 4; ++mf) {
      int mbase = m0 + wm + mf * 16 + kq * 4;
#pragma unroll
      for (int r = 0; r < 4; ++r) C[(size_t)(mbase + r) * ldc + col] = acc[mf][nf][r] + bsum;
    }
  }
}

// ---------------- persistent LSTM recurrence ----------------
// 2 independent barrier groups (batch halves). Block: half=bid&1, gid=bid>>1,
// units U0=gid*32 .. +31; 8 waves; lane (kq,lm): post-MFMA owns gate kq for
// units w*4+0..3 batch lm; after shfl-transpose owns unit w*4+kq, batch lm.
// Whh VGPR-resident (launch_bounds(512,2) -> 256 VGPR budget, no spill).
template <int KT>
__global__ __launch_bounds__(512, 2) void lstm_persist(
    const float* __restrict__ xg, const float* __restrict__ Whh, const float* __restrict__ h0,
    const float* __restrict__ c0, unsigned short* __restrict__ xa, float* __restrict__ out_h,
    float* __restrict__ out_c, int dh, int NG, int* __restrict__ flags) {
  constexpr int KP = KT * 32;
  constexpr int KPP = KP + 8;           // LDS row pad (bf16 elems)
  constexpr int XG = 4 * KP;            // xg row stride
  constexpr int U64R = KP / 4;          // u64 words per h-row
  constexpr int NCH = 16 * U64R;        // staging u64 per step
  constexpr int NIT = (NCH + 511) / 512;

  __shared__ __align__(16) unsigned short hbuf[16 * KPP];

  const int tid = threadIdx.x;
  const int lane = tid & 63;
  const int w = tid >> 6;
  const int lm = lane & 15;
  const int kq = lane >> 4;
  const int bid = blockIdx.x;
  const int half = bid & 1;
  const int gid = bid >> 1;
  const int U0 = gid * 32;
  const int gb = half * 16 + lm;   // this lane's batch
  const int un = U0 + w * 4 + kq;  // this lane's unit (post-transpose)
  const bool vu = un < dh;
  int* gflags = flags + half * NG * 16;

  // ---- Whh -> A-fragments (VGPR-resident) ----
  bf16x8 aw[KT];
  {
    const int ga = lm >> 2, ula = lm & 3;
    const int ua = U0 + w * 4 + ula;
    const bool va = ua < dh;
    const float* wr = Whh + (size_t)(ga * dh + (va ? ua : 0)) * dh;
#pragma unroll
    for (int kt = 0; kt < KT; ++kt) {
      bf16x8 v;
#pragma unroll
      for (int j = 0; j < 8; ++j) {
        int k = kt * 32 + kq * 8 + j;
        v[j] = (__bf16)((va && k < dh) ? wr[k] : 0.0f);
      }
      aw[kt] = v;
    }
  }

  float creg = vu ? c0[gb * dh + un] : 0.0f;

  // ---- publish h0 (row-block 0) ----
  {
    float h0v = vu ? h0[gb * dh + un] : 0.0f;
    unsigned hv = vu ? (unsigned)f2bf(h0v) : 0u;
    unsigned t16 = (unsigned)__shfl_xor((int)hv, 16);
    unsigned v32 = (kq & 1) ? (t16 | (hv << 16)) : (hv | (t16 << 16));
    unsigned o32 = (unsigned)__shfl_xor((int)v32, 32);
    if (kq == 0) {
      unsigned long long pk = (unsigned long long)v32 | ((unsigned long long)o32 << 32);
      __hip_atomic_store((unsigned long long*)(xa + (size_t)gb * KP + U0 + w * 4), pk,
                         __ATOMIC_RELAXED, __HIP_MEMORY_SCOPE_AGENT);
    }
  }
  asm volatile("s_waitcnt vmcnt(0)" ::: "memory");
  __syncthreads();
  if (tid == 0)
    __hip_atomic_store(&gflags[gid * 16], 1, __ATOMIC_RELAXED, __HIP_MEMORY_SCOPE_AGENT);

  for (int t = 0; t < T_; ++t) {
    // xg C-init prefetch (latency hides under poll)
    f32x4 cinit = *(const f32x4*)&xg[(size_t)(t * 32 + gb) * XG + kq * KP + U0 + w * 4];

    // ---- wave0-only poll on this group's NG flags ----
    if (w == 0) {
      const int tgt = t + 1;
      for (;;) {
        int v = (lane < NG) ? __hip_atomic_load(&gflags[lane * 16], __ATOMIC_RELAXED,
                                                __HIP_MEMORY_SCOPE_AGENT)
                            : tgt;
        if (__all(v >= tgt)) break;
      }
    }
    __syncthreads();

    // ---- stage this half's h (row-block t) into LDS, u64 granules ----
    unsigned long long d[NIT];
#pragma unroll
    for (int i = 0; i < NIT; ++i) {
      int c = tid + i * 512;
      if (c < NCH) {
        int row = c / U64R, col = c % U64R;
        d[i] = __hip_atomic_load(
            (const unsigned long long*)(xa + (size_t)(t * 32 + half * 16 + row) * KP) + col,
            __ATOMIC_RELAXED, __HIP_MEMORY_SCOPE_AGENT);
      }
    }
#pragma unroll
    for (int i = 0; i < NIT; ++i) {
      int c = tid + i * 512;
      if (c < NCH) {
        int row = c / U64R, col = c % U64R;
        *(unsigned long long*)((char*)hbuf + (size_t)row * (KPP * 2) + col * 8) = d[i];
      }
    }
    __syncthreads();

    // ---- MFMA: 4 independent chains ----
    f32x4 a0 = cinit;
    f32x4 a1 = {0.f, 0.f, 0.f, 0.f}, a2 = {0.f, 0.f, 0.f, 0.f}, a3 = {0.f, 0.f, 0.f, 0.f};
#pragma unroll
    for (int kt = 0; kt < KT; kt += 4) {
      a0 = __builtin_amdgcn_mfma_f32_16x16x32_bf16(
          aw[kt], *(const bf16x8*)&hbuf[lm * KPP + kt * 32 + kq * 8], a0, 0, 0, 0);
      if (kt + 1 < KT)
        a1 = __builtin_amdgcn_mfma_f32_16x16x32_bf16(
            aw[kt + 1], *(const bf16x8*)&hbuf[lm * KPP + (kt + 1) * 32 + kq * 8], a1, 0, 0, 0);
      if (kt + 2 < KT)
        a2 = __builtin_amdgcn_mfma_f32_16x16x32_bf16(
            aw[kt + 2], *(const bf16x8*)&hbuf[lm * KPP + (kt + 2) * 32 + kq * 8], a2, 0, 0, 0);
      if (kt + 3 < KT)
        a3 = __builtin_amdgcn_mfma_f32_16x16x32_bf16(
            aw[kt + 3], *(const bf16x8*)&hbuf[lm * KPP + (kt + 3) * 32 + kq * 8], a3, 0, 0, 0);
    }
    float av0 = a0[0] + a1[0] + a2[0] + a3[0];
    float av1 = a0[1] + a1[1] + a2[1] + a3[1];
    float av2 = a0[2] + a1[2] + a2[2] + a3[2];
    float av3 = a0[3] + a1[3] + a2[3] + a3[3];

    // ---- 4x4 gate transpose across lanes {lm,16+lm,32+lm,48+lm} ----
    const bool lo1 = (kq & 1) == 0;
    float e0 = lo1 ? av1 : av0;
    float e1 = lo1 ? av3 : av2;
    float r0 = __shfl_xor(e0, 16);
    float r1 = __shfl_xor(e1, 16);
    float b0 = lo1 ? av0 : r0;
    float b1 = lo1 ? r0 : av1;
    float b2 = lo1 ? av2 : r1;
    float b3 = lo1 ? r1 : av3;
    const bool lo2 = (kq & 2) == 0;
    e0 = lo2 ? b2 : b0;
    e1 = lo2 ? b3 : b1;
    r0 = __shfl_xor(e0, 32);
    r1 = __shfl_xor(e1, 32);
    float gi = lo2 ? b0 : r0;
    float gf = lo2 ? b1 : r1;
    float gg = lo2 ? r0 : b2;
    float go = lo2 ? r1 : b3;

    // ---- cell update (fast transcendentals) ----
    float cn = sigf_(gf) * creg + sigf_(gi) * tanhf_(gg);
    float hn = sigf_(go) * tanhf_(cn);
    creg = cn;

    // ---- publish h(t+1): pack 4 units -> u64, one store per 4 lanes ----
    unsigned hv = vu ? (unsigned)f2bf(hn) : 0u;
    unsigned t16 = (unsigned)__shfl_xor((int)hv, 16);
    unsigned v32 = (kq & 1) ? (t16 | (hv << 16)) : (hv | (t16 << 16));
    unsigned o32 = (unsigned)__shfl_xor((int)v32, 32);
    if (kq == 0) {
      unsigned long long pk = (unsigned long long)v32 | ((unsigned long long)o32 << 32);
      __hip_atomic_store(
          (unsigned long long*)(xa + (size_t)((t + 1) * 32 + gb) * KP + U0 + w * 4), pk,
          __ATOMIC_RELAXED, __HIP_MEMORY_SCOPE_AGENT);
    }
    if (t == T_ - 1 && vu) {
      out_h[gb * dh + un] = hn;
      out_c[gb * dh + un] = cn;
    }
    asm volatile("s_waitcnt vmcnt(0)" ::: "memory");
    __syncthreads();
    if (tid == 0)
      __hip_atomic_store(&gflags[gid * 16], t + 2, __ATOMIC_RELAXED, __HIP_MEMORY_SCOPE_AGENT);
  }
}

extern "C" void kernel_launch(void* const* d_in, const int* in_sizes, int n_in, void* d_out,
                              int out_size, void* d_ws, size_t ws_size, hipStream_t stream) {
  const int* input = (const int*)d_in[0];
  const float* emb_W = (const float*)d_in[1];
  const float* final_b = (const float*)d_in[2];

  struct L {
    const float *Wih, *Whh, *bih, *bhh, *h0, *c0;
  };
  L ls[3];
  ls[0] = {(const float*)d_in[3],  (const float*)d_in[4],  (const float*)d_in[5],
           (const float*)d_in[6],  (const float*)d_in[7],  (const float*)d_in[8]};
  ls[1] = {(const float*)d_in[9],  (const float*)d_in[10], (const float*)d_in[11],
           (const float*)d_in[12], (const float*)d_in[13], (const float*)d_in[14]};
  ls[2] = {(const float*)d_in[15], (const float*)d_in[16], (const float*)d_in[17],
           (const float*)d_in[18], (const float*)d_in[19], (const float*)d_in[20]};

  // ---- workspace layout ----
  char* base = (char*)d_ws;
  int* bar = (int*)base;  // 3 layers x 72 flag slots x 64B
  float* xg = (float*)(base + 16384);               // [4096][4608] fp32
  unsigned short* us = (unsigned short*)(xg + (size_t)4096 * 4608);
  unsigned short* embbf = us;                        // [33280][416]
  unsigned short* w0 = embbf + (size_t)33280 * 416;  // [4608][416]
  unsigned short* w1 = w0 + (size_t)4608 * 416;      // [4608][1152]
  unsigned short* w2 = w1 + (size_t)4608 * 1152;     // [1664][1152]
  unsigned short* xa1 = w2 + (size_t)1664 * 1152;    // [4128][1152] L0 h-chain / L1 in
  unsigned short* xa2 = xa1 + (size_t)4128 * 1152;   // [4128][1152] L1 h-chain / L2 in
  unsigned short* xa3 = xa2 + (size_t)4128 * 1152;   // [4128][416]  embed in / L2 h-chain
  float* out = (float*)d_out;

  int* flags0 = bar;
  int* flags1 = bar + 72 * 16;
  int* flags2 = bar + 144 * 16;
  hipMemsetAsync(bar, 0, 16384, stream);

  // ---- conversions ----
  {
    long tot = (long)33280 * 416;
    convW<<<(unsigned)((tot + 255) / 256), 256, 0, stream>>>(emb_W, embbf, V_, E_, 416, tot);
  }
  {
    long tot = (long)4608 * 416;
    convW<<<(unsigned)((tot + 255) / 256), 256, 0, stream>>>(ls[0].Wih, w0, 4600, 400, 416, tot);
  }
  {
    long tot = (long)4608 * 1152;
    convW<<<(unsigned)((tot + 255) / 256), 256, 0, stream>>>(ls[1].Wih, w1, 4600, 1150, 1152, tot);
  }
  {
    long tot = (long)1664 * 1152;
    convW<<<(unsigned)((tot + 255) / 256), 256, 0, stream>>>(ls[2].Wih, w2, 1600, 1150, 1152, tot);
  }
  embed_kernel<<<(T_ * B_ * 416 + 255) / 256, 256, 0, stream>>>(input, emb_W, xa3);

  long o = (long)T_ * B_ * V_;
  float* oh0 = out + o;         float* oc0 = oh0 + 32 * 1150;
  float* oh1 = oc0 + 32 * 1150; float* oc1 = oh1 + 32 * 1150;
  float* oh2 = oc1 + 32 * 1150; float* oc2 = oh2 + 32 * 400;

  // ---- layer 0 ----
  gemm_bf16<<<dim3(36, 32), 256, 0, stream>>>(xa3, w0, ls[0].bih, ls[0].bhh, xg, 4096, 416, 4608,
                                              4600, 1150, 1152);
  lstm_persist<36><<<72, 512, 0, stream>>>(xg, ls[0].Whh, ls[0].h0, ls[0].c0, xa1, oh0, oc0, 1150,
                                           36, flags0);
  // ---- layer 1 ----
  gemm_bf16<<<dim3(36, 32), 256, 0, stream>>>(xa1 + (size_t)32 * 1152, w1, ls[1].bih, ls[1].bhh,
                                              xg, 4096, 1152, 4608, 4600, 1150, 1152);
  lstm_persist<36><<<72, 512, 0, stream>>>(xg, ls[1].Whh, ls[1].h0, ls[1].c0, xa2, oh1, oc1, 1150,
                                           36, flags1);
  // ---- layer 2 ----
  gemm_bf16<<<dim3(13, 32), 256, 0, stream>>>(xa2 + (size_t)32 * 1152, w2, ls[2].bih, ls[2].bhh,
                                              xg, 4096, 1152, 1664, 1600, 400, 416);
  lstm_persist<13><<<26, 512, 0, stream>>>(xg, ls[2].Whh, ls[2].h0, ls[2].c0, xa3, oh2, oc2, 400,
                                           13, flags2);
  // ---- tied decoder ----
  gemm_bf16<<<dim3(260, 32), 256, 0, stream>>>(xa3 + (size_t)32 * 416, embbf, final_b, nullptr,
                                               out, 4096, 416, V_, V_, 0, 0);
}